// Round 3
// baseline (7597.622 us; speedup 1.0000x reference)
//
#include <hip/hip_runtime.h>
#include <math.h>

// Problem constants
#define B_TOT   2048
#define N_IN    1024
#define N_H     1024
#define N_OUT   512
#define N_UPD   1536
#define T_TOT   3072   // MAX_STEPS * N_UPD

// ---------------- prep kernels ----------------

// W1T[c*1024 + r] = W1[r*1024 + c]
__global__ void prep_w1t(const float* __restrict__ W1, float* __restrict__ W1T) {
    int idx = blockIdx.x * 256 + threadIdx.x;   // < 1024*1024
    int r = idx & 1023;
    int c = idx >> 10;
    W1T[(size_t)c * 1024 + r] = W1[(size_t)r * 1024 + c];
}

// W2Tf[c*512 + r] = W2[r*1024 + c]
__global__ void prep_w2tf(const float* __restrict__ W2, float* __restrict__ W2Tf) {
    int idx = blockIdx.x * 256 + threadIdx.x;   // < 512*1024
    int r = idx & 511;
    int c = idx >> 9;
    W2Tf[(size_t)c * 512 + r] = W2[(size_t)r * 1024 + c];
}

// WHd[n][lane][j] = (double)W2[(j*64+lane)][n]   (hidden-flip fragment, fp64)
__global__ void prep_whd(const float* __restrict__ W2, double* __restrict__ WHd) {
    int idx = blockIdx.x * 256 + threadIdx.x;   // < 1024*512
    int n = idx >> 9;
    int r = idx & 511;
    int l = r >> 3, j = r & 7;
    WHd[idx] = (double)W2[(size_t)(j * 64 + l) * 1024 + n];
}

// WOd[nn][lane][j] = (double)W2[nn][j*64+lane]   (output-flip fragment, fp64)
__global__ void prep_wod(const float* __restrict__ W2, double* __restrict__ WOd) {
    int idx = blockIdx.x * 256 + threadIdx.x;   // < 512*1024
    int nn = idx >> 10;
    int r = idx & 1023;
    int l = r >> 4, j = r & 15;
    WOd[idx] = (double)W2[(size_t)nn * 1024 + j * 64 + l];
}

// out[b][0:1024] = x[b][:]   (visible layer copy, out row stride 2560)
__global__ void copy_x(const float* __restrict__ x, float* __restrict__ out) {
    int idx = blockIdx.x * 256 + threadIdx.x;   // < 2048*256 (float4 units)
    int b = idx >> 8, c = idx & 255;
    ((float4*)(out + (size_t)b * 2560))[c] = ((const float4*)(x + (size_t)b * 1024))[c];
}

// ---------------- init fields (fp64, bit-identical add order) ----------------
// 4 batch rows per block -> 512 blocks (2/CU), masks 4-bit.
__global__ __launch_bounds__(256) void init_fields(
    const float* __restrict__ x, const float* __restrict__ s1i, const float* __restrict__ s2i,
    const float* __restrict__ W1T, const float* __restrict__ W2, const float* __restrict__ W2Tf,
    const float* __restrict__ b1, const float* __restrict__ b2,
    double* __restrict__ h1g, double* __restrict__ h2g)
{
    const int tid = threadIdx.x;
    const int b0 = blockIdx.x * 4;

    __shared__ unsigned char xm[1024];
    __shared__ unsigned char s2msk[512];
    __shared__ unsigned char s1msk[1024];

    for (int i = tid; i < 1024; i += 256) {
        unsigned m = 0;
        #pragma unroll
        for (int b = 0; b < 4; ++b) m |= (x[(size_t)(b0 + b) * 1024 + i] != 0.0f) << b;
        xm[i] = (unsigned char)m;
    }
    for (int j = tid; j < 512; j += 256) {
        unsigned m = 0;
        #pragma unroll
        for (int b = 0; b < 4; ++b) m |= (s2i[(size_t)(b0 + b) * 512 + j] != 0.0f) << b;
        s2msk[j] = (unsigned char)m;
    }
    for (int j = tid; j < 1024; j += 256) {
        unsigned m = 0;
        #pragma unroll
        for (int b = 0; b < 4; ++b) m |= (s1i[(size_t)(b0 + b) * 1024 + j] != 0.0f) << b;
        s1msk[j] = (unsigned char)m;
    }
    __syncthreads();

    double h1r[16];   // h1r[k*4+b], m = k*256 + tid
    #pragma unroll
    for (int k = 0; k < 4; ++k) {
        double bv = (double)b1[k * 256 + tid];
        #pragma unroll
        for (int b = 0; b < 4; ++b) h1r[k * 4 + b] = bv;
    }
    double h2r[8];    // h2r[k*4+b], m' = k*256 + tid
    #pragma unroll
    for (int k = 0; k < 2; ++k) {
        double bv = (double)b2[k * 256 + tid];
        #pragma unroll
        for (int b = 0; b < 4; ++b) h2r[k * 4 + b] = bv;
    }

    // part 1: x @ W1^T
    {
        const unsigned* xmu = (const unsigned*)xm;
        unsigned mwn = xmu[0];
        for (int g = 0; g < 256; ++g) {
            unsigned mg = (unsigned)__builtin_amdgcn_readfirstlane((int)mwn);
            if (g + 1 < 256) mwn = xmu[g + 1];
            float wr[4][4];
            #pragma unroll
            for (int s = 0; s < 4; ++s) {
                const float* q = W1T + (size_t)(4 * g + s) * 1024 + tid;
                wr[s][0] = q[0]; wr[s][1] = q[256]; wr[s][2] = q[512]; wr[s][3] = q[768];
            }
            #pragma unroll
            for (int s = 0; s < 4; ++s) {
                unsigned m4 = (mg >> (8 * s)) & 0xFu;
                if (m4) {
                    double d0 = (double)wr[s][0], d1 = (double)wr[s][1];
                    double d2 = (double)wr[s][2], d3 = (double)wr[s][3];
                    #pragma unroll
                    for (int b = 0; b < 4; ++b) if ((m4 >> b) & 1u) {
                        h1r[0 * 4 + b] += d0; h1r[1 * 4 + b] += d1;
                        h1r[2 * 4 + b] += d2; h1r[3 * 4 + b] += d3;
                    }
                }
            }
        }
    }
    // part 2: s2 @ W2
    {
        const unsigned* s2u = (const unsigned*)s2msk;
        unsigned mwn = s2u[0];
        for (int g = 0; g < 128; ++g) {
            unsigned mg = (unsigned)__builtin_amdgcn_readfirstlane((int)mwn);
            if (g + 1 < 128) mwn = s2u[g + 1];
            float wr[4][4];
            #pragma unroll
            for (int s = 0; s < 4; ++s) {
                const float* q = W2 + (size_t)(4 * g + s) * 1024 + tid;
                wr[s][0] = q[0]; wr[s][1] = q[256]; wr[s][2] = q[512]; wr[s][3] = q[768];
            }
            #pragma unroll
            for (int s = 0; s < 4; ++s) {
                unsigned m4 = (mg >> (8 * s)) & 0xFu;
                if (m4) {
                    double d0 = (double)wr[s][0], d1 = (double)wr[s][1];
                    double d2 = (double)wr[s][2], d3 = (double)wr[s][3];
                    #pragma unroll
                    for (int b = 0; b < 4; ++b) if ((m4 >> b) & 1u) {
                        h1r[0 * 4 + b] += d0; h1r[1 * 4 + b] += d1;
                        h1r[2 * 4 + b] += d2; h1r[3 * 4 + b] += d3;
                    }
                }
            }
        }
    }
    // part 3: s1 @ W2^T
    {
        const unsigned* s1u = (const unsigned*)s1msk;
        unsigned mwn = s1u[0];
        for (int g = 0; g < 256; ++g) {
            unsigned mg = (unsigned)__builtin_amdgcn_readfirstlane((int)mwn);
            if (g + 1 < 256) mwn = s1u[g + 1];
            float wr[4][2];
            #pragma unroll
            for (int s = 0; s < 4; ++s) {
                const float* q = W2Tf + (size_t)(4 * g + s) * 512 + tid;
                wr[s][0] = q[0]; wr[s][1] = q[256];
            }
            #pragma unroll
            for (int s = 0; s < 4; ++s) {
                unsigned m4 = (mg >> (8 * s)) & 0xFu;
                if (m4) {
                    double d0 = (double)wr[s][0], d1 = (double)wr[s][1];
                    #pragma unroll
                    for (int b = 0; b < 4; ++b) if ((m4 >> b) & 1u) {
                        h2r[0 * 4 + b] += d0; h2r[1 * 4 + b] += d1;
                    }
                }
            }
        }
    }

    #pragma unroll
    for (int k = 0; k < 4; ++k)
        #pragma unroll
        for (int b = 0; b < 4; ++b)
            h1g[(size_t)(b0 + b) * 1024 + k * 256 + tid] = h1r[k * 4 + b];
    #pragma unroll
    for (int k = 0; k < 2; ++k)
        #pragma unroll
        for (int b = 0; b < 4; ++b)
            h2g[(size_t)(b0 + b) * 512 + k * 256 + tid] = h2r[k * 4 + b];
}

// ---------------- Gibbs chain: ONE batch row per wave, no barriers ----------------

__device__ __forceinline__ double rdl_f64(double v, int sl) {
    union { double d; int i[2]; } a, b;
    a.d = v;
    b.i[0] = __builtin_amdgcn_readlane(a.i[0], sl);
    b.i[1] = __builtin_amdgcn_readlane(a.i[1], sl);
    return b.d;
}

__global__ __launch_bounds__(64, 2) void gibbs(
    const float* __restrict__ u, const int* __restrict__ ids,
    const double* __restrict__ WHd, const double* __restrict__ WOd,
    const double* __restrict__ h1g, const double* __restrict__ h2g,
    const float* __restrict__ s1i, const float* __restrict__ s2i,
    float* __restrict__ out)
{
    const int lane = threadIdx.x;          // 0..63
    const int b = blockIdx.x;              // batch row

    // fields in registers: unit m = k*64 + lane
    double h1r[16], h2r[8];
    #pragma unroll
    for (int k = 0; k < 16; ++k) h1r[k] = h1g[(size_t)b * 1024 + k * 64 + lane];
    #pragma unroll
    for (int k = 0; k < 8; ++k)  h2r[k] = h2g[(size_t)b * 512 + k * 64 + lane];

    // state as wave-uniform 64-bit masks (SALU-resident): bit `lane` of s1u[k] = s1[k*64+lane]
    unsigned long long s1u[16], s2u[8];
    #pragma unroll
    for (int k = 0; k < 16; ++k) s1u[k] = __ballot(s1i[(size_t)b * 1024 + k * 64 + lane] != 0.0f);
    #pragma unroll
    for (int k = 0; k < 8; ++k)  s2u[k] = __ballot(s2i[(size_t)b * 512 + k * 64 + lane] != 0.0f);

    // temperature (identical formula to prior passing rounds)
    const double T1c = (double)(float)(2.0 / exp((double)1 / 5.0));
    auto thrcalc = [&](float uv, int tp) -> double {
        double T = (tp >= N_UPD) ? T1c : 2.0;
        double ud = (double)uv;
        return T * (log(ud) - log1p(-ud));
    };

    // threshold ring: lane l of window holds thr for step win+l
    double tc, tn; float uP;
    {
        float uA = u[(size_t)(0 + lane) * 2048 + b];
        float uB = u[(size_t)(64 + lane) * 2048 + b];
        uP       = u[(size_t)(128 + lane) * 2048 + b];
        tc = thrcalc(uA, 0 + lane);
        tn = thrcalc(uB, 64 + lane);
    }

    double wA[16], wB[16], wC[16], wD[16];
    auto loadw = [&](int n, double (&w)[16]) {
        if (n < N_H) {
            const double2* p = (const double2*)(WHd + ((size_t)n << 9) + (lane << 3));
            double2 a = p[0], bb = p[1], c = p[2], d = p[3];
            w[0] = a.x; w[1] = a.y; w[2] = bb.x; w[3] = bb.y;
            w[4] = c.x; w[5] = c.y; w[6] = d.x;  w[7] = d.y;
        } else {
            const double2* p = (const double2*)(WOd + ((size_t)(n - N_H) << 10) + (lane << 4));
            double2 a = p[0], bb = p[1], c = p[2], d = p[3];
            double2 e = p[4], f = p[5], g = p[6], h = p[7];
            w[0]  = a.x; w[1]  = a.y; w[2]  = bb.x; w[3]  = bb.y;
            w[4]  = c.x; w[5]  = c.y; w[6]  = d.x;  w[7]  = d.y;
            w[8]  = e.x; w[9]  = e.y; w[10] = f.x;  w[11] = f.y;
            w[12] = g.x; w[13] = g.y; w[14] = h.x;  w[15] = h.y;
        }
    };

    auto step = [&](int t, const double (&w)[16], int n) {
        int sl = t & 63;
        double th = rdl_f64(tc, sl);
        if (n < N_H) {
            int k = n >> 6, ow = n & 63;
            double hv = h1r[0];
            #pragma unroll
            for (int kk = 1; kk < 16; ++kk) if (k == kk) hv = h1r[kk];
            unsigned long long m = __ballot(hv > th);
            int a = (int)((m >> ow) & 1ull);
            unsigned long long ob = s1u[0];
            #pragma unroll
            for (int kk = 1; kk < 16; ++kk) if (k == kk) ob = s1u[kk];
            int o = (int)((ob >> ow) & 1ull);
            int d = a - o;
            if (d) {
                unsigned long long nb = ob ^ (1ull << ow);
                #pragma unroll
                for (int kk = 0; kk < 16; ++kk) if (k == kk) s1u[kk] = nb;
                double sd = (double)d;
                #pragma unroll
                for (int j = 0; j < 8; ++j) h2r[j] = fma(sd, w[j], h2r[j]);
            }
        } else {
            int nn = n - N_H;
            int k = nn >> 6, ow = nn & 63;
            double hv = h2r[0];
            #pragma unroll
            for (int kk = 1; kk < 8; ++kk) if (k == kk) hv = h2r[kk];
            unsigned long long m = __ballot(hv > th);
            int a = (int)((m >> ow) & 1ull);
            unsigned long long ob = s2u[0];
            #pragma unroll
            for (int kk = 1; kk < 8; ++kk) if (k == kk) ob = s2u[kk];
            int o = (int)((ob >> ow) & 1ull);
            int d = a - o;
            if (d) {
                unsigned long long nb = ob ^ (1ull << ow);
                #pragma unroll
                for (int kk = 0; kk < 8; ++kk) if (k == kk) s2u[kk] = nb;
                double sd = (double)d;
                #pragma unroll
                for (int j = 0; j < 16; ++j) h1r[j] = fma(sd, w[j], h1r[j]);
            }
        }
    };

    // depth-4 row prefetch, ids prefetched 8 ahead (uniform scalar loads)
    int n0 = ids[0], n1 = ids[1], n2 = ids[2], n3 = ids[3];
    int p0 = ids[4], p1 = ids[5], p2 = ids[6], p3 = ids[7];
    loadw(n0, wA); loadw(n1, wB); loadw(n2, wC); loadw(n3, wD);

    for (int t = 0; t < T_TOT; t += 4) {
        step(t,     wA, n0); loadw(p0, wA);
        step(t + 1, wB, n1); loadw(p1, wB);
        step(t + 2, wC, n2); loadw(p2, wC);
        step(t + 3, wD, n3); loadw(p3, wD);
        n0 = p0; n1 = p1; n2 = p2; n3 = p3;
        int tb = t + 8;
        p0 = ids[tb     < T_TOT ? tb     : T_TOT - 1];
        p1 = ids[tb + 1 < T_TOT ? tb + 1 : T_TOT - 1];
        p2 = ids[tb + 2 < T_TOT ? tb + 2 : T_TOT - 1];
        p3 = ids[tb + 3 < T_TOT ? tb + 3 : T_TOT - 1];
        if (((t + 4) & 63) == 0 && (t + 4) < T_TOT) {
            tc = tn;
            tn = thrcalc(uP, t + 68 + lane);
            int tp = t + 132 + lane; if (tp > T_TOT - 1) tp = T_TOT - 1;
            uP = u[(size_t)tp * 2048 + b];
        }
    }

    // epilogue: s1 | s2 into out row (x copied by copy_x kernel)
    #pragma unroll
    for (int k = 0; k < 16; ++k)
        out[(size_t)b * 2560 + 1024 + k * 64 + lane] = (float)((s1u[k] >> lane) & 1ull);
    #pragma unroll
    for (int k = 0; k < 8; ++k)
        out[(size_t)b * 2560 + 2048 + k * 64 + lane] = (float)((s2u[k] >> lane) & 1ull);
}

// ---------------- launch ----------------
extern "C" void kernel_launch(void* const* d_in, const int* in_sizes, int n_in,
                              void* d_out, int out_size, void* d_ws, size_t ws_size,
                              hipStream_t stream) {
    const float* x   = (const float*)d_in[0];
    const float* s1i = (const float*)d_in[1];
    const float* s2i = (const float*)d_in[2];
    const float* W1  = (const float*)d_in[3];
    const float* b1  = (const float*)d_in[4];
    const float* W2  = (const float*)d_in[5];
    const float* b2  = (const float*)d_in[6];
    const float* u   = (const float*)d_in[7];
    const int*   ids = (const int*)d_in[8];
    float* out = (float*)d_out;

    char* ws = (char*)d_ws;
    float*  W1T  = (float*) (ws);                       //  4 MB
    float*  W2Tf = (float*) (ws + ((size_t)4  << 20));  //  2 MB
    double* WHd  = (double*)(ws + ((size_t)6  << 20));  //  4 MB
    double* WOd  = (double*)(ws + ((size_t)10 << 20));  //  8 MB
    double* h1g  = (double*)(ws + ((size_t)18 << 20));  // 16 MB
    double* h2g  = (double*)(ws + ((size_t)34 << 20));  //  8 MB  (total 42 MB)

    hipLaunchKernelGGL(prep_w1t,  dim3(4096), dim3(256), 0, stream, W1, W1T);
    hipLaunchKernelGGL(prep_w2tf, dim3(2048), dim3(256), 0, stream, W2, W2Tf);
    hipLaunchKernelGGL(prep_whd,  dim3(2048), dim3(256), 0, stream, W2, WHd);
    hipLaunchKernelGGL(prep_wod,  dim3(2048), dim3(256), 0, stream, W2, WOd);
    hipLaunchKernelGGL(copy_x,    dim3(2048), dim3(256), 0, stream, x, out);
    hipLaunchKernelGGL(init_fields, dim3(512), dim3(256), 0, stream,
                       x, s1i, s2i, W1T, W2, W2Tf, b1, b2, h1g, h2g);
    hipLaunchKernelGGL(gibbs, dim3(2048), dim3(64), 0, stream,
                       u, ids, WHd, WOd, h1g, h2g, s1i, s2i, out);
}

// Round 4
// 2034.309 us; speedup vs baseline: 3.7347x; 3.7347x over previous
//
#include <hip/hip_runtime.h>
#include <math.h>

// Problem constants
#define B_TOT   2048
#define N_IN    1024
#define N_H     1024
#define N_OUT   512
#define N_UPD   1536
#define T_TOT   3072   // MAX_STEPS * N_UPD
#define N_WIN   48     // T_TOT / 64

// ---------------- prep kernels ----------------

// W1T[c*1024 + r] = W1[r*1024 + c]
__global__ void prep_w1t(const float* __restrict__ W1, float* __restrict__ W1T) {
    int idx = blockIdx.x * 256 + threadIdx.x;   // < 1024*1024
    int r = idx & 1023;
    int c = idx >> 10;
    W1T[(size_t)c * 1024 + r] = W1[(size_t)r * 1024 + c];
}

// W2Tf[c*512 + r] = W2[r*1024 + c]
__global__ void prep_w2tf(const float* __restrict__ W2, float* __restrict__ W2Tf) {
    int idx = blockIdx.x * 256 + threadIdx.x;   // < 512*1024
    int r = idx & 511;
    int c = idx >> 9;
    W2Tf[(size_t)c * 512 + r] = W2[(size_t)r * 1024 + c];
}

// WHf[n][lane][j] = W2[(j*64+lane)][n]   (hidden-flip fragment, fp32)
__global__ void prep_whf(const float* __restrict__ W2, float* __restrict__ WHf) {
    int idx = blockIdx.x * 256 + threadIdx.x;   // < 1024*512
    int n = idx >> 9;
    int r = idx & 511;
    int l = r >> 3, j = r & 7;
    WHf[idx] = W2[(size_t)(j * 64 + l) * 1024 + n];
}

// WOf[nn][lane][j] = W2[nn][j*64+lane]   (output-flip fragment, fp32)
__global__ void prep_wof(const float* __restrict__ W2, float* __restrict__ WOf) {
    int idx = blockIdx.x * 256 + threadIdx.x;   // < 512*1024
    int nn = idx >> 10;
    int r = idx & 1023;
    int l = r >> 4, j = r & 15;
    WOf[idx] = W2[(size_t)nn * 1024 + j * 64 + l];
}

// Wx[w][j][l]: fp64 coupling of flip at step w*64+j onto decision at step w*64+l.
// Zero when same layer (incl. j==l). 48*64*64 entries.
__global__ void prep_wx(const float* __restrict__ W2, const int* __restrict__ ids,
                        double* __restrict__ WX) {
    int idx = blockIdx.x * 256 + threadIdx.x;   // < 48*4096
    int w = idx >> 12;
    int j = (idx >> 6) & 63;
    int l = idx & 63;
    int mj = ids[w * 64 + j];
    int nl = ids[w * 64 + l];
    double v = 0.0;
    if (mj < N_H && nl >= N_H) v = (double)W2[(size_t)(nl - N_H) * 1024 + mj];
    else if (mj >= N_H && nl < N_H) v = (double)W2[(size_t)(mj - N_H) * 1024 + nl];
    WX[idx] = v;
}

// posA[n] = sweep-1 step of unit n; posB[n] = sweep-2 step - 1536
__global__ void prep_pos(const int* __restrict__ ids, int* __restrict__ posA,
                         int* __restrict__ posB) {
    int t = blockIdx.x * 256 + threadIdx.x;   // < 3072
    int n = ids[t];
    if (t < N_UPD) posA[n] = t; else posB[n] = t - N_UPD;
}

// out[b][0:1024] = x[b][:]
__global__ void copy_x(const float* __restrict__ x, float* __restrict__ out) {
    int idx = blockIdx.x * 256 + threadIdx.x;   // < 2048*256 (float4 units)
    int b = idx >> 8, c = idx & 255;
    ((float4*)(out + (size_t)b * 2560))[c] = ((const float4*)(x + (size_t)b * 1024))[c];
}

// ---------------- init fields (fp64, bit-identical add order) ----------------
// 2 batch rows per block -> 1024 blocks (4/CU).
__global__ __launch_bounds__(256) void init_fields(
    const float* __restrict__ x, const float* __restrict__ s1i, const float* __restrict__ s2i,
    const float* __restrict__ W1T, const float* __restrict__ W2, const float* __restrict__ W2Tf,
    const float* __restrict__ b1, const float* __restrict__ b2,
    double* __restrict__ h1g, double* __restrict__ h2g)
{
    const int tid = threadIdx.x;
    const int b0 = blockIdx.x * 2;

    __shared__ unsigned char xm[1024];
    __shared__ unsigned char s2msk[512];
    __shared__ unsigned char s1msk[1024];

    for (int i = tid; i < 1024; i += 256) {
        unsigned m = 0;
        #pragma unroll
        for (int b = 0; b < 2; ++b) m |= (x[(size_t)(b0 + b) * 1024 + i] != 0.0f) << b;
        xm[i] = (unsigned char)m;
    }
    for (int j = tid; j < 512; j += 256) {
        unsigned m = 0;
        #pragma unroll
        for (int b = 0; b < 2; ++b) m |= (s2i[(size_t)(b0 + b) * 512 + j] != 0.0f) << b;
        s2msk[j] = (unsigned char)m;
    }
    for (int j = tid; j < 1024; j += 256) {
        unsigned m = 0;
        #pragma unroll
        for (int b = 0; b < 2; ++b) m |= (s1i[(size_t)(b0 + b) * 1024 + j] != 0.0f) << b;
        s1msk[j] = (unsigned char)m;
    }
    __syncthreads();

    double h1r[8];   // h1r[k*2+b], m = k*256 + tid
    #pragma unroll
    for (int k = 0; k < 4; ++k) {
        double bv = (double)b1[k * 256 + tid];
        #pragma unroll
        for (int b = 0; b < 2; ++b) h1r[k * 2 + b] = bv;
    }
    double h2r[4];   // h2r[k*2+b]
    #pragma unroll
    for (int k = 0; k < 2; ++k) {
        double bv = (double)b2[k * 256 + tid];
        #pragma unroll
        for (int b = 0; b < 2; ++b) h2r[k * 2 + b] = bv;
    }

    // part 1: x @ W1^T
    {
        const unsigned* xmu = (const unsigned*)xm;
        unsigned mwn = xmu[0];
        for (int g = 0; g < 256; ++g) {
            unsigned mg = (unsigned)__builtin_amdgcn_readfirstlane((int)mwn);
            if (g + 1 < 256) mwn = xmu[g + 1];
            float wr[4][4];
            #pragma unroll
            for (int s = 0; s < 4; ++s) {
                const float* q = W1T + (size_t)(4 * g + s) * 1024 + tid;
                wr[s][0] = q[0]; wr[s][1] = q[256]; wr[s][2] = q[512]; wr[s][3] = q[768];
            }
            #pragma unroll
            for (int s = 0; s < 4; ++s) {
                unsigned m2 = (mg >> (8 * s)) & 0x3u;
                if (m2) {
                    double d0 = (double)wr[s][0], d1 = (double)wr[s][1];
                    double d2 = (double)wr[s][2], d3 = (double)wr[s][3];
                    #pragma unroll
                    for (int b = 0; b < 2; ++b) if ((m2 >> b) & 1u) {
                        h1r[0 * 2 + b] += d0; h1r[1 * 2 + b] += d1;
                        h1r[2 * 2 + b] += d2; h1r[3 * 2 + b] += d3;
                    }
                }
            }
        }
    }
    // part 2: s2 @ W2
    {
        const unsigned* s2u = (const unsigned*)s2msk;
        unsigned mwn = s2u[0];
        for (int g = 0; g < 128; ++g) {
            unsigned mg = (unsigned)__builtin_amdgcn_readfirstlane((int)mwn);
            if (g + 1 < 128) mwn = s2u[g + 1];
            float wr[4][4];
            #pragma unroll
            for (int s = 0; s < 4; ++s) {
                const float* q = W2 + (size_t)(4 * g + s) * 1024 + tid;
                wr[s][0] = q[0]; wr[s][1] = q[256]; wr[s][2] = q[512]; wr[s][3] = q[768];
            }
            #pragma unroll
            for (int s = 0; s < 4; ++s) {
                unsigned m2 = (mg >> (8 * s)) & 0x3u;
                if (m2) {
                    double d0 = (double)wr[s][0], d1 = (double)wr[s][1];
                    double d2 = (double)wr[s][2], d3 = (double)wr[s][3];
                    #pragma unroll
                    for (int b = 0; b < 2; ++b) if ((m2 >> b) & 1u) {
                        h1r[0 * 2 + b] += d0; h1r[1 * 2 + b] += d1;
                        h1r[2 * 2 + b] += d2; h1r[3 * 2 + b] += d3;
                    }
                }
            }
        }
    }
    // part 3: s1 @ W2^T
    {
        const unsigned* s1u = (const unsigned*)s1msk;
        unsigned mwn = s1u[0];
        for (int g = 0; g < 256; ++g) {
            unsigned mg = (unsigned)__builtin_amdgcn_readfirstlane((int)mwn);
            if (g + 1 < 256) mwn = s1u[g + 1];
            float wr[4][2];
            #pragma unroll
            for (int s = 0; s < 4; ++s) {
                const float* q = W2Tf + (size_t)(4 * g + s) * 512 + tid;
                wr[s][0] = q[0]; wr[s][1] = q[256];
            }
            #pragma unroll
            for (int s = 0; s < 4; ++s) {
                unsigned m2 = (mg >> (8 * s)) & 0x3u;
                if (m2) {
                    double d0 = (double)wr[s][0], d1 = (double)wr[s][1];
                    #pragma unroll
                    for (int b = 0; b < 2; ++b) if ((m2 >> b) & 1u) {
                        h2r[0 * 2 + b] += d0; h2r[1 * 2 + b] += d1;
                    }
                }
            }
        }
    }

    #pragma unroll
    for (int k = 0; k < 4; ++k)
        #pragma unroll
        for (int b = 0; b < 2; ++b)
            h1g[(size_t)(b0 + b) * 1024 + k * 256 + tid] = h1r[k * 2 + b];
    #pragma unroll
    for (int k = 0; k < 2; ++k)
        #pragma unroll
        for (int b = 0; b < 2; ++b)
            h2g[(size_t)(b0 + b) * 512 + k * 256 + tid] = h2r[k * 2 + b];
}

// ---------------- Gibbs chain: windowed, one wave per batch row ----------------

__global__ __launch_bounds__(64, 2) void gibbs(
    const float* __restrict__ u, const int* __restrict__ ids,
    const float* __restrict__ WHf, const float* __restrict__ WOf,
    const double* __restrict__ WX,
    const int* __restrict__ posA, const int* __restrict__ posB,
    const double* __restrict__ h1g, const double* __restrict__ h2g,
    const float* __restrict__ s1i, const float* __restrict__ s2i,
    float* __restrict__ out)
{
    const int lane = threadIdx.x;          // 0..63
    const int b = blockIdx.x;              // batch row

    __shared__ double fld[1536];                 // field mirror, unit-indexed
    __shared__ unsigned long long act[N_WIN];    // decision bits per window

    // master fields in registers: unit m = k*64 + lane
    double h1r[16], h2r[8];
    #pragma unroll
    for (int k = 0; k < 16; ++k) h1r[k] = h1g[(size_t)b * 1024 + k * 64 + lane];
    #pragma unroll
    for (int k = 0; k < 8; ++k)  h2r[k] = h2g[(size_t)b * 512 + k * 64 + lane];

    const double T1c = (double)(float)(2.0 / exp((double)1 / 5.0));

    auto loadrow = [&](int n, float (&w)[16]) {
        if (n < N_H) {
            const float4* p = (const float4*)(WHf + ((size_t)n << 9) + (lane << 3));
            float4 a = p[0], bb = p[1];
            w[0] = a.x; w[1] = a.y; w[2] = a.z; w[3] = a.w;
            w[4] = bb.x; w[5] = bb.y; w[6] = bb.z; w[7] = bb.w;
        } else {
            const float4* p = (const float4*)(WOf + ((size_t)(n - N_H) << 10) + (lane << 4));
            float4 a = p[0], bb = p[1], c = p[2], d = p[3];
            w[0]  = a.x; w[1]  = a.y; w[2]  = a.z; w[3]  = a.w;
            w[4]  = bb.x; w[5]  = bb.y; w[6]  = bb.z; w[7]  = bb.w;
            w[8]  = c.x; w[9]  = c.y; w[10] = c.z; w[11] = c.w;
            w[12] = d.x; w[13] = d.y; w[14] = d.z; w[15] = d.w;
        }
    };

    // prefetch window 0 ids / uniforms
    int idw = ids[lane];
    float uw = u[(size_t)lane * 2048 + b];

    for (int w = 0; w < N_WIN; ++w) {
        const int t0 = w * 64;

        // prefetch next window's ids / uniforms early
        int idn = 0; float un = 0.0f;
        if (w + 1 < N_WIN) {
            idn = ids[t0 + 64 + lane];
            un  = u[(size_t)(t0 + 64 + lane) * 2048 + b];
        }

        // old state bit of this window's unit (lane l -> step t0+l)
        int oldb;
        if (w < 24) {
            float sv = (idw < N_H) ? s1i[(size_t)b * 1024 + idw]
                                   : s2i[(size_t)b * 512 + (idw - N_H)];
            oldb = (sv != 0.0f) ? 1 : 0;
        } else {
            int p = posA[idw];
            unsigned long long av = act[p >> 6];
            oldb = (int)((av >> (p & 63)) & 1ull);
        }
        unsigned long long OLD = __ballot(oldb != 0);

        // threshold for this lane's step (T is window-uniform; boundary aligned)
        double T = (t0 >= N_UPD) ? T1c : 2.0;
        double ud = (double)uw;
        double th = T * (log(ud) - log1p(-ud));

        // mirror master fields to LDS, gather decision scalar g = h[n_l]
        #pragma unroll
        for (int k = 0; k < 16; ++k) fld[k * 64 + lane] = h1r[k];
        #pragma unroll
        for (int k = 0; k < 8; ++k)  fld[1024 + k * 64 + lane] = h2r[k];
        double g = fld[idw];

        // serial 64-step decision loop; wx prefetched 16 deep
        const double* wxp = WX + ((size_t)w << 12) + lane;   // Wx[w][j][l]
        double wxbuf[16];
        #pragma unroll
        for (int j = 0; j < 16; ++j) wxbuf[j] = wxp[(size_t)j * 64];

        unsigned long long A = 0;
        for (int jo = 0; jo < 64; jo += 16) {
            #pragma unroll
            for (int ji = 0; ji < 16; ++ji) {
                const int j = jo + ji;
                unsigned long long m = __ballot(g > th);
                int a = (int)((m >> j) & 1ull);
                int o = (int)((OLD >> j) & 1ull);
                A |= ((unsigned long long)a) << j;
                double sd = (double)(a - o);
                g = fma(sd, wxbuf[ji], g);
                if (j + 16 < 64) wxbuf[ji] = wxp[(size_t)(j + 16) * 64];
            }
        }
        if (lane == 0) act[w] = A;

        // bulk rank-1 apply for flipped steps, ascending j, groups of 4
        unsigned long long C = A ^ OLD;
        auto applyrow = [&](int j, int n, const float (&r)[16]) {
            double sd = ((A >> j) & 1ull) ? 1.0 : -1.0;
            if (n < N_H) {
                #pragma unroll
                for (int jj = 0; jj < 8; ++jj) h2r[jj] = fma(sd, (double)r[jj], h2r[jj]);
            } else {
                #pragma unroll
                for (int jj = 0; jj < 16; ++jj) h1r[jj] = fma(sd, (double)r[jj], h1r[jj]);
            }
        };
        while (C) {
            int j0 = __builtin_ctzll(C); C &= C - 1;
            int j1 = -1, j2 = -1, j3 = -1;
            if (C) { j1 = __builtin_ctzll(C); C &= C - 1;
                if (C) { j2 = __builtin_ctzll(C); C &= C - 1;
                    if (C) { j3 = __builtin_ctzll(C); C &= C - 1; } } }
            int n0 = __builtin_amdgcn_readlane(idw, j0);
            int n1 = (j1 >= 0) ? __builtin_amdgcn_readlane(idw, j1) : 0;
            int n2 = (j2 >= 0) ? __builtin_amdgcn_readlane(idw, j2) : 0;
            int n3 = (j3 >= 0) ? __builtin_amdgcn_readlane(idw, j3) : 0;
            float r0[16], r1[16], r2[16], r3[16];
            loadrow(n0, r0);
            if (j1 >= 0) loadrow(n1, r1);
            if (j2 >= 0) loadrow(n2, r2);
            if (j3 >= 0) loadrow(n3, r3);
            applyrow(j0, n0, r0);
            if (j1 >= 0) applyrow(j1, n1, r1);
            if (j2 >= 0) applyrow(j2, n2, r2);
            if (j3 >= 0) applyrow(j3, n3, r3);
        }

        idw = idn; uw = un;
    }

    // epilogue: final states = sweep-2 decision bits
    #pragma unroll
    for (int k = 0; k < 16; ++k) {
        int n = k * 64 + lane;
        int p = posB[n];
        unsigned long long av = act[24 + (p >> 6)];
        out[(size_t)b * 2560 + 1024 + n] = (float)((av >> (p & 63)) & 1ull);
    }
    #pragma unroll
    for (int k = 0; k < 8; ++k) {
        int n2 = k * 64 + lane;
        int p = posB[1024 + n2];
        unsigned long long av = act[24 + (p >> 6)];
        out[(size_t)b * 2560 + 2048 + n2] = (float)((av >> (p & 63)) & 1ull);
    }
}

// ---------------- launch ----------------
extern "C" void kernel_launch(void* const* d_in, const int* in_sizes, int n_in,
                              void* d_out, int out_size, void* d_ws, size_t ws_size,
                              hipStream_t stream) {
    const float* x   = (const float*)d_in[0];
    const float* s1i = (const float*)d_in[1];
    const float* s2i = (const float*)d_in[2];
    const float* W1  = (const float*)d_in[3];
    const float* b1  = (const float*)d_in[4];
    const float* W2  = (const float*)d_in[5];
    const float* b2  = (const float*)d_in[6];
    const float* u   = (const float*)d_in[7];
    const int*   ids = (const int*)d_in[8];
    float* out = (float*)d_out;

    char* ws = (char*)d_ws;
    float*  W1T  = (float*) (ws);                        //  4 MB
    float*  W2Tf = (float*) (ws + ((size_t)4  << 20));   //  2 MB
    float*  WHf  = (float*) (ws + ((size_t)6  << 20));   //  2 MB
    float*  WOf  = (float*) (ws + ((size_t)8  << 20));   //  2 MB
    double* WX   = (double*)(ws + ((size_t)10 << 20));   //  1.5 MB (48*4096*8)
    int*    posA = (int*)   (ws + ((size_t)12 << 20));   //  6 KB
    int*    posB = (int*)   (ws + ((size_t)12 << 20) + 8192);
    double* h1g  = (double*)(ws + ((size_t)13 << 20));   // 16 MB
    double* h2g  = (double*)(ws + ((size_t)29 << 20));   //  8 MB  (total 37 MB)

    hipLaunchKernelGGL(prep_w1t,  dim3(4096), dim3(256), 0, stream, W1, W1T);
    hipLaunchKernelGGL(prep_w2tf, dim3(2048), dim3(256), 0, stream, W2, W2Tf);
    hipLaunchKernelGGL(prep_whf,  dim3(2048), dim3(256), 0, stream, W2, WHf);
    hipLaunchKernelGGL(prep_wof,  dim3(2048), dim3(256), 0, stream, W2, WOf);
    hipLaunchKernelGGL(prep_wx,   dim3(768),  dim3(256), 0, stream, W2, ids, WX);
    hipLaunchKernelGGL(prep_pos,  dim3(12),   dim3(256), 0, stream, ids, posA, posB);
    hipLaunchKernelGGL(copy_x,    dim3(2048), dim3(256), 0, stream, x, out);
    hipLaunchKernelGGL(init_fields, dim3(1024), dim3(256), 0, stream,
                       x, s1i, s2i, W1T, W2, W2Tf, b1, b2, h1g, h2g);
    hipLaunchKernelGGL(gibbs, dim3(2048), dim3(64), 0, stream,
                       u, ids, WHf, WOf, WX, posA, posB, h1g, h2g, s1i, s2i, out);
}

// Round 5
// 1487.062 us; speedup vs baseline: 5.1092x; 1.3680x over previous
//
#include <hip/hip_runtime.h>
#include <math.h>

// Problem constants
#define B_TOT   2048
#define N_IN    1024
#define N_H     1024
#define N_OUT   512
#define N_UPD   1536
#define T_TOT   3072   // MAX_STEPS * N_UPD
#define N_WIN   48     // T_TOT / 64

// ---------------- prep kernels ----------------

// W1T[c*1024 + r] = W1[r*1024 + c]
__global__ void prep_w1t(const float* __restrict__ W1, float* __restrict__ W1T) {
    int idx = blockIdx.x * 256 + threadIdx.x;   // < 1024*1024
    int r = idx & 1023;
    int c = idx >> 10;
    W1T[(size_t)c * 1024 + r] = W1[(size_t)r * 1024 + c];
}

// W2Tf[c*512 + r] = W2[r*1024 + c]
__global__ void prep_w2tf(const float* __restrict__ W2, float* __restrict__ W2Tf) {
    int idx = blockIdx.x * 256 + threadIdx.x;   // < 512*1024
    int r = idx & 511;
    int c = idx >> 9;
    W2Tf[(size_t)c * 512 + r] = W2[(size_t)r * 1024 + c];
}

// WHf[n][lane][j] = W2[(j*64+lane)][n]   (hidden-flip fragment, fp32, j fast 0..7)
__global__ void prep_whf(const float* __restrict__ W2, float* __restrict__ WHf) {
    int idx = blockIdx.x * 256 + threadIdx.x;   // < 1024*512
    int n = idx >> 9;
    int r = idx & 511;
    int l = r >> 3, j = r & 7;
    WHf[idx] = W2[(size_t)(j * 64 + l) * 1024 + n];
}

// WOf[nn][lane][j] = W2[nn][j*64+lane]   (output-flip fragment, fp32, j fast 0..15)
__global__ void prep_wof(const float* __restrict__ W2, float* __restrict__ WOf) {
    int idx = blockIdx.x * 256 + threadIdx.x;   // < 512*1024
    int nn = idx >> 10;
    int r = idx & 1023;
    int l = r >> 4, j = r & 15;
    WOf[idx] = W2[(size_t)nn * 1024 + j * 64 + l];
}

// WXf[w][j][l]: fp32 coupling of flip at step w*64+j onto decision at step w*64+l.
__global__ void prep_wx(const float* __restrict__ W2, const int* __restrict__ ids,
                        float* __restrict__ WXf) {
    int idx = blockIdx.x * 256 + threadIdx.x;   // < 48*4096
    int w = idx >> 12;
    int j = (idx >> 6) & 63;
    int l = idx & 63;
    int mj = ids[w * 64 + j];
    int nl = ids[w * 64 + l];
    float v = 0.0f;
    if (mj < N_H && nl >= N_H) v = W2[(size_t)(nl - N_H) * 1024 + mj];
    else if (mj >= N_H && nl < N_H) v = W2[(size_t)(mj - N_H) * 1024 + nl];
    WXf[idx] = v;
}

// posA[n] = sweep-1 step of unit n; posB[n] = sweep-2 step - 1536
__global__ void prep_pos(const int* __restrict__ ids, int* __restrict__ posA,
                         int* __restrict__ posB) {
    int t = blockIdx.x * 256 + threadIdx.x;   // < 3072
    int n = ids[t];
    if (t < N_UPD) posA[n] = t; else posB[n] = t - N_UPD;
}

// pos2[t] = posA[ids[1536 + t]]  (coalesced sweep-2 old-state locator)
__global__ void prep_pos2(const int* __restrict__ ids, const int* __restrict__ posA,
                          int* __restrict__ pos2) {
    int t = blockIdx.x * 256 + threadIdx.x;   // < 1536
    pos2[t] = posA[ids[N_UPD + t]];
}

// uT[b][t] = u[t][b]  (LDS-tiled transpose)
__global__ __launch_bounds__(256) void prep_ut(const float* __restrict__ u,
                                               float* __restrict__ uT) {
    __shared__ float tile[64][65];
    int bt = blockIdx.x % 48;
    int bb = blockIdx.x / 48;
    int tx = threadIdx.x & 63;
    int ty0 = threadIdx.x >> 6;   // 0..3
    for (int r = ty0; r < 64; r += 4)
        tile[r][tx] = u[(size_t)(bt * 64 + r) * 2048 + bb * 64 + tx];
    __syncthreads();
    for (int r = ty0; r < 64; r += 4)
        uT[(size_t)(bb * 64 + r) * 3072 + bt * 64 + tx] = tile[tx][r];
}

// out[b][0:1024] = x[b][:]
__global__ void copy_x(const float* __restrict__ x, float* __restrict__ out) {
    int idx = blockIdx.x * 256 + threadIdx.x;   // < 2048*256 (float4 units)
    int b = idx >> 8, c = idx & 255;
    ((float4*)(out + (size_t)b * 2560))[c] = ((const float4*)(x + (size_t)b * 1024))[c];
}

// ---------------- init fields (fp64, bit-identical add order) ----------------
__global__ __launch_bounds__(256) void init_fields(
    const float* __restrict__ x, const float* __restrict__ s1i, const float* __restrict__ s2i,
    const float* __restrict__ W1T, const float* __restrict__ W2, const float* __restrict__ W2Tf,
    const float* __restrict__ b1, const float* __restrict__ b2,
    double* __restrict__ h1g, double* __restrict__ h2g)
{
    const int tid = threadIdx.x;
    const int b0 = blockIdx.x * 2;

    __shared__ unsigned char xm[1024];
    __shared__ unsigned char s2msk[512];
    __shared__ unsigned char s1msk[1024];

    for (int i = tid; i < 1024; i += 256) {
        unsigned m = 0;
        #pragma unroll
        for (int b = 0; b < 2; ++b) m |= (x[(size_t)(b0 + b) * 1024 + i] != 0.0f) << b;
        xm[i] = (unsigned char)m;
    }
    for (int j = tid; j < 512; j += 256) {
        unsigned m = 0;
        #pragma unroll
        for (int b = 0; b < 2; ++b) m |= (s2i[(size_t)(b0 + b) * 512 + j] != 0.0f) << b;
        s2msk[j] = (unsigned char)m;
    }
    for (int j = tid; j < 1024; j += 256) {
        unsigned m = 0;
        #pragma unroll
        for (int b = 0; b < 2; ++b) m |= (s1i[(size_t)(b0 + b) * 1024 + j] != 0.0f) << b;
        s1msk[j] = (unsigned char)m;
    }
    __syncthreads();

    double h1r[8];   // h1r[k*2+b], m = k*256 + tid
    #pragma unroll
    for (int k = 0; k < 4; ++k) {
        double bv = (double)b1[k * 256 + tid];
        #pragma unroll
        for (int b = 0; b < 2; ++b) h1r[k * 2 + b] = bv;
    }
    double h2r[4];
    #pragma unroll
    for (int k = 0; k < 2; ++k) {
        double bv = (double)b2[k * 256 + tid];
        #pragma unroll
        for (int b = 0; b < 2; ++b) h2r[k * 2 + b] = bv;
    }

    // part 1: x @ W1^T  (1-group-deep weight prefetch; add order unchanged)
    {
        const unsigned* xmu = (const unsigned*)xm;
        unsigned mwn = xmu[0];
        float wc[16];
        #pragma unroll
        for (int s = 0; s < 4; ++s) {
            const float* q = W1T + (size_t)s * 1024 + tid;
            wc[s*4+0] = q[0]; wc[s*4+1] = q[256]; wc[s*4+2] = q[512]; wc[s*4+3] = q[768];
        }
        for (int g = 0; g < 256; ++g) {
            unsigned mg = (unsigned)__builtin_amdgcn_readfirstlane((int)mwn);
            if (g + 1 < 256) mwn = xmu[g + 1];
            float wn[16];
            if (g + 1 < 256) {
                #pragma unroll
                for (int s = 0; s < 4; ++s) {
                    const float* q = W1T + (size_t)(4 * (g + 1) + s) * 1024 + tid;
                    wn[s*4+0] = q[0]; wn[s*4+1] = q[256]; wn[s*4+2] = q[512]; wn[s*4+3] = q[768];
                }
            } else {
                #pragma unroll
                for (int z = 0; z < 16; ++z) wn[z] = wc[z];
            }
            #pragma unroll
            for (int s = 0; s < 4; ++s) {
                unsigned m2 = (mg >> (8 * s)) & 0x3u;
                if (m2) {
                    double d0 = (double)wc[s*4+0], d1 = (double)wc[s*4+1];
                    double d2 = (double)wc[s*4+2], d3 = (double)wc[s*4+3];
                    #pragma unroll
                    for (int b = 0; b < 2; ++b) if ((m2 >> b) & 1u) {
                        h1r[0 * 2 + b] += d0; h1r[1 * 2 + b] += d1;
                        h1r[2 * 2 + b] += d2; h1r[3 * 2 + b] += d3;
                    }
                }
            }
            #pragma unroll
            for (int z = 0; z < 16; ++z) wc[z] = wn[z];
        }
    }
    // part 2: s2 @ W2
    {
        const unsigned* s2u = (const unsigned*)s2msk;
        unsigned mwn = s2u[0];
        float wc[16];
        #pragma unroll
        for (int s = 0; s < 4; ++s) {
            const float* q = W2 + (size_t)s * 1024 + tid;
            wc[s*4+0] = q[0]; wc[s*4+1] = q[256]; wc[s*4+2] = q[512]; wc[s*4+3] = q[768];
        }
        for (int g = 0; g < 128; ++g) {
            unsigned mg = (unsigned)__builtin_amdgcn_readfirstlane((int)mwn);
            if (g + 1 < 128) mwn = s2u[g + 1];
            float wn[16];
            if (g + 1 < 128) {
                #pragma unroll
                for (int s = 0; s < 4; ++s) {
                    const float* q = W2 + (size_t)(4 * (g + 1) + s) * 1024 + tid;
                    wn[s*4+0] = q[0]; wn[s*4+1] = q[256]; wn[s*4+2] = q[512]; wn[s*4+3] = q[768];
                }
            } else {
                #pragma unroll
                for (int z = 0; z < 16; ++z) wn[z] = wc[z];
            }
            #pragma unroll
            for (int s = 0; s < 4; ++s) {
                unsigned m2 = (mg >> (8 * s)) & 0x3u;
                if (m2) {
                    double d0 = (double)wc[s*4+0], d1 = (double)wc[s*4+1];
                    double d2 = (double)wc[s*4+2], d3 = (double)wc[s*4+3];
                    #pragma unroll
                    for (int b = 0; b < 2; ++b) if ((m2 >> b) & 1u) {
                        h1r[0 * 2 + b] += d0; h1r[1 * 2 + b] += d1;
                        h1r[2 * 2 + b] += d2; h1r[3 * 2 + b] += d3;
                    }
                }
            }
            #pragma unroll
            for (int z = 0; z < 16; ++z) wc[z] = wn[z];
        }
    }
    // part 3: s1 @ W2^T
    {
        const unsigned* s1u = (const unsigned*)s1msk;
        unsigned mwn = s1u[0];
        float wc[8];
        #pragma unroll
        for (int s = 0; s < 4; ++s) {
            const float* q = W2Tf + (size_t)s * 512 + tid;
            wc[s*2+0] = q[0]; wc[s*2+1] = q[256];
        }
        for (int g = 0; g < 256; ++g) {
            unsigned mg = (unsigned)__builtin_amdgcn_readfirstlane((int)mwn);
            if (g + 1 < 256) mwn = s1u[g + 1];
            float wn[8];
            if (g + 1 < 256) {
                #pragma unroll
                for (int s = 0; s < 4; ++s) {
                    const float* q = W2Tf + (size_t)(4 * (g + 1) + s) * 512 + tid;
                    wn[s*2+0] = q[0]; wn[s*2+1] = q[256];
                }
            } else {
                #pragma unroll
                for (int z = 0; z < 8; ++z) wn[z] = wc[z];
            }
            #pragma unroll
            for (int s = 0; s < 4; ++s) {
                unsigned m2 = (mg >> (8 * s)) & 0x3u;
                if (m2) {
                    double d0 = (double)wc[s*2+0], d1 = (double)wc[s*2+1];
                    #pragma unroll
                    for (int b = 0; b < 2; ++b) if ((m2 >> b) & 1u) {
                        h2r[0 * 2 + b] += d0; h2r[1 * 2 + b] += d1;
                    }
                }
            }
            #pragma unroll
            for (int z = 0; z < 8; ++z) wc[z] = wn[z];
        }
    }

    #pragma unroll
    for (int k = 0; k < 4; ++k)
        #pragma unroll
        for (int b = 0; b < 2; ++b)
            h1g[(size_t)(b0 + b) * 1024 + k * 256 + tid] = h1r[k * 2 + b];
    #pragma unroll
    for (int k = 0; k < 2; ++k)
        #pragma unroll
        for (int b = 0; b < 2; ++b)
            h2g[(size_t)(b0 + b) * 512 + k * 256 + tid] = h2r[k * 2 + b];
}

// ---------------- Gibbs chain: windowed, one wave per batch row ----------------

__global__ __launch_bounds__(64, 2) void gibbs(
    const float* __restrict__ uT, const int* __restrict__ ids,
    const float* __restrict__ WHf, const float* __restrict__ WOf,
    const float* __restrict__ WXf,
    const int* __restrict__ pos2, const int* __restrict__ posB,
    const double* __restrict__ h1g, const double* __restrict__ h2g,
    const float* __restrict__ s1i, const float* __restrict__ s2i,
    float* __restrict__ out)
{
    const int lane = threadIdx.x;          // 0..63
    const int b = blockIdx.x;              // batch row

    __shared__ double fld[1536];                 // field mirror, unit-indexed
    __shared__ unsigned long long act[N_WIN];    // decision bits per window
    __shared__ unsigned long long sb[24];        // initial-state bits

    // master fields in registers: unit m = k*64 + lane
    double h1r[16], h2r[8];
    #pragma unroll
    for (int k = 0; k < 16; ++k) h1r[k] = h1g[(size_t)b * 1024 + k * 64 + lane];
    #pragma unroll
    for (int k = 0; k < 8; ++k)  h2r[k] = h2g[(size_t)b * 512 + k * 64 + lane];

    // pack initial state into LDS bitmasks (coalesced reads + ballots)
    #pragma unroll
    for (int k = 0; k < 16; ++k) {
        unsigned long long m = __ballot(s1i[(size_t)b * 1024 + k * 64 + lane] != 0.0f);
        if (lane == 0) sb[k] = m;
    }
    #pragma unroll
    for (int k = 0; k < 8; ++k) {
        unsigned long long m = __ballot(s2i[(size_t)b * 512 + k * 64 + lane] != 0.0f);
        if (lane == 0) sb[16 + k] = m;
    }

    const double T1c = (double)(float)(2.0 / exp((double)1 / 5.0));

    // window-0 setup
    int idw = ids[lane];
    float uw = uT[(size_t)b * 3072 + lane];
    int p2c = 0;
    double thc;
    {
        double ud = (double)uw;
        thc = 2.0 * (log(ud) - log1p(-ud));
    }

    for (int w = 0; w < N_WIN; ++w) {
        const int t0 = w * 64;

        // issue next-window loads early (consumed after the decision loop)
        int idn = 0; float un = 0.0f; int p2n = 0;
        if (w + 1 < N_WIN) {
            idn = ids[t0 + 64 + lane];
            un  = uT[(size_t)b * 3072 + t0 + 64 + lane];
            if (w + 1 >= 24) p2n = pos2[(w + 1 - 24) * 64 + lane];
        }

        // old state of this window's unit
        int oldb;
        if (w < 24) {
            unsigned long long sv = sb[idw >> 6];
            oldb = (int)((sv >> (idw & 63)) & 1ull);
        } else {
            unsigned long long av = act[p2c >> 6];
            oldb = (int)((av >> (p2c & 63)) & 1ull);
        }
        unsigned long long OLD = __ballot(oldb != 0);

        // mirror master fields, gather decision scalar
        #pragma unroll
        for (int k = 0; k < 16; ++k) fld[k * 64 + lane] = h1r[k];
        #pragma unroll
        for (int k = 0; k < 8; ++k)  fld[1024 + k * 64 + lane] = h2r[k];
        double g = fld[idw];

        // decision loop, depth-8 wx prefetch (fp32 -> f64 conversion off chain)
        const float* wxp = WXf + ((size_t)w << 12) + lane;
        double wxd[8];
        #pragma unroll
        for (int j = 0; j < 8; ++j) wxd[j] = (double)wxp[(size_t)j * 64];

        unsigned long long A = 0;
        for (int jo = 0; jo < 64; jo += 8) {
            #pragma unroll
            for (int ji = 0; ji < 8; ++ji) {
                const int j = jo + ji;
                unsigned long long m = __ballot(g > thc);
                unsigned long long a = (m >> j) & 1ull;
                A |= a << j;
                int d = (int)a - (int)((OLD >> j) & 1ull);
                g = fma((double)d, wxd[ji], g);
                if (jo + 8 < 64) wxd[ji] = (double)wxp[(size_t)(j + 8) * 64];
            }
        }
        if (lane == 0) act[w] = A;

        // next-window threshold (overlaps the apply phase)
        double thn = 0.0;
        if (w + 1 < N_WIN) {
            double T = (w + 1 >= 24) ? T1c : 2.0;
            double ud = (double)un;
            thn = T * (log(ud) - log1p(-ud));
        }

        // bulk rank-1 apply for flipped steps (ascending j, 1-deep row prefetch,
        // explicit float4 registers only -- no arrays, no lambdas)
        unsigned long long C = A ^ OLD;
        if (C) {
            int jc = __builtin_ctzll(C);
            unsigned long long Cr = C & (C - 1);
            int nc = __builtin_amdgcn_readlane(idw, jc);
            float4 c0, c1, c2, c3;
            if (nc < N_H) {
                const float4* p = (const float4*)(WHf + ((size_t)nc << 9) + (lane << 3));
                c0 = p[0]; c1 = p[1]; c2 = c1; c3 = c1;
            } else {
                const float4* p = (const float4*)(WOf + ((size_t)(nc - N_H) << 10) + (lane << 4));
                c0 = p[0]; c1 = p[1]; c2 = p[2]; c3 = p[3];
            }
            while (true) {
                int jn = 64, nn = 0;
                float4 d0, d1, d2, d3;
                bool have_next = (Cr != 0);
                if (have_next) {
                    jn = __builtin_ctzll(Cr); Cr &= Cr - 1;
                    nn = __builtin_amdgcn_readlane(idw, jn);
                    if (nn < N_H) {
                        const float4* p = (const float4*)(WHf + ((size_t)nn << 9) + (lane << 3));
                        d0 = p[0]; d1 = p[1]; d2 = d1; d3 = d1;
                    } else {
                        const float4* p = (const float4*)(WOf + ((size_t)(nn - N_H) << 10) + (lane << 4));
                        d0 = p[0]; d1 = p[1]; d2 = p[2]; d3 = p[3];
                    }
                } else {
                    d0 = c0; d1 = c1; d2 = c2; d3 = c3;
                }
                double sd = ((A >> jc) & 1ull) ? 1.0 : -1.0;
                if (nc < N_H) {
                    h2r[0] = fma(sd, (double)c0.x, h2r[0]);
                    h2r[1] = fma(sd, (double)c0.y, h2r[1]);
                    h2r[2] = fma(sd, (double)c0.z, h2r[2]);
                    h2r[3] = fma(sd, (double)c0.w, h2r[3]);
                    h2r[4] = fma(sd, (double)c1.x, h2r[4]);
                    h2r[5] = fma(sd, (double)c1.y, h2r[5]);
                    h2r[6] = fma(sd, (double)c1.z, h2r[6]);
                    h2r[7] = fma(sd, (double)c1.w, h2r[7]);
                } else {
                    h1r[0]  = fma(sd, (double)c0.x, h1r[0]);
                    h1r[1]  = fma(sd, (double)c0.y, h1r[1]);
                    h1r[2]  = fma(sd, (double)c0.z, h1r[2]);
                    h1r[3]  = fma(sd, (double)c0.w, h1r[3]);
                    h1r[4]  = fma(sd, (double)c1.x, h1r[4]);
                    h1r[5]  = fma(sd, (double)c1.y, h1r[5]);
                    h1r[6]  = fma(sd, (double)c1.z, h1r[6]);
                    h1r[7]  = fma(sd, (double)c1.w, h1r[7]);
                    h1r[8]  = fma(sd, (double)c2.x, h1r[8]);
                    h1r[9]  = fma(sd, (double)c2.y, h1r[9]);
                    h1r[10] = fma(sd, (double)c2.z, h1r[10]);
                    h1r[11] = fma(sd, (double)c2.w, h1r[11]);
                    h1r[12] = fma(sd, (double)c3.x, h1r[12]);
                    h1r[13] = fma(sd, (double)c3.y, h1r[13]);
                    h1r[14] = fma(sd, (double)c3.z, h1r[14]);
                    h1r[15] = fma(sd, (double)c3.w, h1r[15]);
                }
                if (!have_next) break;
                jc = jn; nc = nn;
                c0 = d0; c1 = d1; c2 = d2; c3 = d3;
            }
        }

        idw = idn; uw = un; p2c = p2n; thc = thn;
    }

    // epilogue: final states = sweep-2 decision bits (posB coalesced)
    #pragma unroll
    for (int k = 0; k < 16; ++k) {
        int p = posB[k * 64 + lane];
        unsigned long long av = act[24 + (p >> 6)];
        out[(size_t)b * 2560 + 1024 + k * 64 + lane] = (float)((av >> (p & 63)) & 1ull);
    }
    #pragma unroll
    for (int k = 0; k < 8; ++k) {
        int p = posB[1024 + k * 64 + lane];
        unsigned long long av = act[24 + (p >> 6)];
        out[(size_t)b * 2560 + 2048 + k * 64 + lane] = (float)((av >> (p & 63)) & 1ull);
    }
}

// ---------------- launch ----------------
extern "C" void kernel_launch(void* const* d_in, const int* in_sizes, int n_in,
                              void* d_out, int out_size, void* d_ws, size_t ws_size,
                              hipStream_t stream) {
    const float* x   = (const float*)d_in[0];
    const float* s1i = (const float*)d_in[1];
    const float* s2i = (const float*)d_in[2];
    const float* W1  = (const float*)d_in[3];
    const float* b1  = (const float*)d_in[4];
    const float* W2  = (const float*)d_in[5];
    const float* b2  = (const float*)d_in[6];
    const float* u   = (const float*)d_in[7];
    const int*   ids = (const int*)d_in[8];
    float* out = (float*)d_out;

    char* ws = (char*)d_ws;
    float*  W1T  = (float*) (ws);                               //  4 MB
    float*  W2Tf = (float*) (ws + ((size_t)4  << 20));          //  2 MB
    float*  WHf  = (float*) (ws + ((size_t)6  << 20));          //  2 MB
    float*  WOf  = (float*) (ws + ((size_t)8  << 20));          //  2 MB
    float*  WXf  = (float*) (ws + ((size_t)10 << 20));          //  768 KB
    int*    posA = (int*)   (ws + ((size_t)11 << 20));          //  6 KB
    int*    posB = (int*)   (ws + ((size_t)11 << 20) + 8192);   //  6 KB
    int*    pos2 = (int*)   (ws + ((size_t)11 << 20) + 16384);  //  6 KB
    float*  uTp  = (float*) (ws + ((size_t)12 << 20));          // 24 MB
    double* h1g  = (double*)(ws + ((size_t)36 << 20));          // 16 MB
    double* h2g  = (double*)(ws + ((size_t)52 << 20));          //  8 MB (total 60 MB)

    hipLaunchKernelGGL(prep_w1t,  dim3(4096), dim3(256), 0, stream, W1, W1T);
    hipLaunchKernelGGL(prep_w2tf, dim3(2048), dim3(256), 0, stream, W2, W2Tf);
    hipLaunchKernelGGL(prep_whf,  dim3(2048), dim3(256), 0, stream, W2, WHf);
    hipLaunchKernelGGL(prep_wof,  dim3(2048), dim3(256), 0, stream, W2, WOf);
    hipLaunchKernelGGL(prep_wx,   dim3(768),  dim3(256), 0, stream, W2, ids, WXf);
    hipLaunchKernelGGL(prep_pos,  dim3(12),   dim3(256), 0, stream, ids, posA, posB);
    hipLaunchKernelGGL(prep_pos2, dim3(6),    dim3(256), 0, stream, ids, posA, pos2);
    hipLaunchKernelGGL(prep_ut,   dim3(1536), dim3(256), 0, stream, u, uTp);
    hipLaunchKernelGGL(copy_x,    dim3(2048), dim3(256), 0, stream, x, out);
    hipLaunchKernelGGL(init_fields, dim3(1024), dim3(256), 0, stream,
                       x, s1i, s2i, W1T, W2, W2Tf, b1, b2, h1g, h2g);
    hipLaunchKernelGGL(gibbs, dim3(2048), dim3(64), 0, stream,
                       uTp, ids, WHf, WOf, WXf, pos2, posB, h1g, h2g, s1i, s2i, out);
}